// Round 10
// baseline (31.670 us; speedup 1.0000x reference)
//
#include <hip/hip_runtime.h>

typedef _Float16 f16;
typedef _Float16 f16x8 __attribute__((ext_vector_type(8)));
typedef float f32x16 __attribute__((ext_vector_type(16)));
typedef float f32x4 __attribute__((ext_vector_type(4)));

#define APITCH 264   // f16 units; 528 B pitch

// ============================================================================
// single kernel: 512 blocks x 512 threads (8 waves), 32 rows/block,
// wave tile 32x32. No prep, no ws: B-fragments are built in-register from
// read-only R (hot in every XCD L2 across all iterations).
//   mm1 B (lane l, elem j) = f16 hi/lo of 256*R[32wv+(l&31)][16ks+8(l>>5)+j]
//     -> per-lane row-major f32x8 load (2 x f32x4, offset immediates)
//   mm2 B (lane l, elem j) = f16 of R[16ks+8(l>>5)+j][32wv+(l&31)]
//     -> 8 scalar dword loads; each j covers 2 x 128B contiguous segments
// ============================================================================
__global__ __launch_bounds__(512, 4) void tq_main(
    const float* __restrict__ X, const float* __restrict__ R,
    const float* __restrict__ CB, float* __restrict__ OUT) {
  __shared__ f16 A1h[32][APITCH];
  __shared__ f16 A1l[32][APITCH];
  __shared__ f16 Qs[32][APITCH];
  __shared__ float s2s[32];

  const int tid = threadIdx.x;
  const int lane = tid & 63;
  const int wv = tid >> 6;       // 0..7 = 32-col group
  const int lrow = lane & 31;
  const int kg = lane >> 5;
  const long row0 = (long)blockIdx.x * 32;

  // ---- issue x loads first ----
  const int r = tid >> 4, q = tid & 15;
  const float* xp = X + (row0 + r) * 256 + q * 16;
  float xa[16];
  #pragma unroll
  for (int i = 0; i < 4; ++i) {
    f32x4 v = ((const f32x4*)xp)[i];
    xa[4 * i] = v.x; xa[4 * i + 1] = v.y; xa[4 * i + 2] = v.z; xa[4 * i + 3] = v.w;
  }

  // ---- issue mm1 depth-4 raw-B preloads from R rows (L2-hot, read-only) ----
  const float* p1 = R + (32 * wv + lrow) * 256 + 8 * kg;
  f32x4 bA0 = *(const f32x4*)(p1 + 0);
  f32x4 bB0 = *(const f32x4*)(p1 + 4);
  f32x4 bA1 = *(const f32x4*)(p1 + 16);
  f32x4 bB1 = *(const f32x4*)(p1 + 20);
  f32x4 bA2 = *(const f32x4*)(p1 + 32);
  f32x4 bB2 = *(const f32x4*)(p1 + 36);
  f32x4 bA3 = *(const f32x4*)(p1 + 48);
  f32x4 bB3 = *(const f32x4*)(p1 + 52);

  // ---- codebook load issued early ----
  float cbf[16];
  #pragma unroll
  for (int i = 0; i < 16; ++i) cbf[i] = CB[i];

  // ---- wave-local norm via shfl (16 threads/row) ----
  float ss = 0.f;
  #pragma unroll
  for (int i = 0; i < 16; ++i) ss += xa[i] * xa[i];
  ss += __shfl_xor(ss, 8, 16);
  ss += __shfl_xor(ss, 4, 16);
  ss += __shfl_xor(ss, 2, 16);
  ss += __shfl_xor(ss, 1, 16);
  float nrm = fmaxf(sqrtf(ss), 1e-8f);
  float s1f = 4096.0f / nrm;         // y_raw = 65536 * y_scaled
  if (q == 0) s2s[r] = nrm * 0.0625f;

  // ---- split A = x*s1 into f16 hi/lo -> LDS ----
  #pragma unroll
  for (int c8 = 0; c8 < 2; ++c8) {
    f16x8 h, l;
    #pragma unroll
    for (int j = 0; j < 8; ++j) {
      float a = xa[c8 * 8 + j] * s1f;
      f16 hh = (f16)a;
      h[j] = hh;
      l[j] = (f16)(a - (float)hh);
    }
    *(f16x8*)&A1h[r][q * 16 + c8 * 8] = h;
    *(f16x8*)&A1l[r][q * 16 + c8 * 8] = l;
  }
  __syncthreads();

  // ---- mm1: depth-4 raw prefetch, in-register f16 split of B, 3-term ----
  f32x16 zv;
  #pragma unroll
  for (int i = 0; i < 16; ++i) zv[i] = 0.0f;
  f32x16 accH = zv, accL = zv;

#define MM1_STAGE(BA, BB, KS)                                                   \
  {                                                                             \
    const int k0 = (KS) * 16 + kg * 8;                                          \
    f16x8 ah = *(const f16x8*)&A1h[lrow][k0];                                   \
    f16x8 al = *(const f16x8*)&A1l[lrow][k0];                                   \
    f16x8 bh, bl;                                                               \
    _Pragma("unroll")                                                           \
    for (int j = 0; j < 4; ++j) {                                               \
      float v = BA[j] * 256.0f;                                                 \
      f16 hh = (f16)v;                                                          \
      bh[j] = hh;                                                               \
      bl[j] = (f16)(v - (float)hh);                                             \
    }                                                                           \
    _Pragma("unroll")                                                           \
    for (int j = 0; j < 4; ++j) {                                               \
      float v = BB[j] * 256.0f;                                                 \
      f16 hh = (f16)v;                                                          \
      bh[4 + j] = hh;                                                           \
      bl[4 + j] = (f16)(v - (float)hh);                                         \
    }                                                                           \
    accH = __builtin_amdgcn_mfma_f32_32x32x16_f16(ah, bh, accH, 0, 0, 0);       \
    accL = __builtin_amdgcn_mfma_f32_32x32x16_f16(al, bh, accL, 0, 0, 0);       \
    accH = __builtin_amdgcn_mfma_f32_32x32x16_f16(ah, bl, accH, 0, 0, 0);       \
    BA = *(const f32x4*)(p1 + (((KS) + 4) & 15) * 16);                          \
    BB = *(const f32x4*)(p1 + (((KS) + 4) & 15) * 16 + 4);                      \
  }

  #pragma unroll
  for (int ksb = 0; ksb < 16; ksb += 4) {
    MM1_STAGE(bA0, bB0, ksb)
    MM1_STAGE(bA1, bB1, ksb + 1)
    MM1_STAGE(bA2, bB2, ksb + 2)
    MM1_STAGE(bA3, bB3, ksb + 3)
  }
#undef MM1_STAGE

  // ---- issue mm2 depth-4 preloads (column gather; hides under quantize) ----
  const float* p2 = R + (8 * kg) * 256 + 32 * wv + lrow;
#define MM2_LOAD(CV, KS)                                                        \
  {                                                                             \
    CV[0] = p2[(KS) * 4096 + 0 * 256];                                          \
    CV[1] = p2[(KS) * 4096 + 1 * 256];                                          \
    CV[2] = p2[(KS) * 4096 + 2 * 256];                                          \
    CV[3] = p2[(KS) * 4096 + 3 * 256];                                          \
    CV[4] = p2[(KS) * 4096 + 4 * 256];                                          \
    CV[5] = p2[(KS) * 4096 + 5 * 256];                                          \
    CV[6] = p2[(KS) * 4096 + 6 * 256];                                          \
    CV[7] = p2[(KS) * 4096 + 7 * 256];                                          \
  }
  float c0[8], c1[8], c2[8], c3[8];
  MM2_LOAD(c0, 0)
  MM2_LOAD(c1, 1)
  MM2_LOAD(c2, 2)
  MM2_LOAD(c3, 3)

  // ---- midpoints / packed codebook ----
  float M[15];
  #pragma unroll
  for (int t = 0; t < 15; ++t) M[t] = 65536.0f * (0.5f * (cbf[t] + cbf[t + 1]));
  unsigned int cpk[8];
  #pragma unroll
  for (int i = 0; i < 8; ++i) {
    unsigned short lb = __builtin_bit_cast(unsigned short, (f16)cbf[2 * i]);
    unsigned short hb = __builtin_bit_cast(unsigned short, (f16)cbf[2 * i + 1]);
    cpk[i] = ((unsigned int)hb << 16) | (unsigned int)lb;
  }

  // ---- quantize -> Qs (own region): id = 8b3+4b2+2b1+b0 ----
  #pragma unroll
  for (int rr = 0; rr < 16; ++rr) {
    float y = accH[rr] + accL[rr];
    int row = 4 * kg + (rr & 3) + 8 * (rr >> 2);
    int kk = 32 * wv + lrow;
    bool b3 = y > M[7];
    float m2 = b3 ? M[11] : M[3];
    bool b2 = y > m2;
    float m1 = b3 ? (b2 ? M[13] : M[9]) : (b2 ? M[5] : M[1]);
    bool b1 = y > m1;
    float m0 = b1 ? (b3 ? (b2 ? M[14] : M[10]) : (b2 ? M[6] : M[2]))
                  : (b3 ? (b2 ? M[12] : M[8]) : (b2 ? M[4] : M[0]));
    bool b0 = y > m0;
    unsigned int pp = b3 ? (b2 ? (b1 ? cpk[7] : cpk[6]) : (b1 ? cpk[5] : cpk[4]))
                         : (b2 ? (b1 ? cpk[3] : cpk[2]) : (b1 ? cpk[1] : cpk[0]));
    unsigned short qb = (unsigned short)(b0 ? (pp >> 16) : (pp & 0xFFFFu));
    Qs[row][kk] = __builtin_bit_cast(f16, qb);
  }
  __syncthreads();   // all Qs writes visible before mm2 reads

  // ---- mm2: depth-4 rotation, 2 acc chains, convert-on-use ----
  f32x16 acc2a = zv, acc2b = zv;

#define MM2_STAGE(CV, ACC, KS)                                                  \
  {                                                                             \
    f16x8 qa = *(const f16x8*)&Qs[lrow][(KS) * 16 + kg * 8];                    \
    f16x8 b2;                                                                   \
    _Pragma("unroll")                                                           \
    for (int j = 0; j < 8; ++j) b2[j] = (f16)CV[j];                             \
    ACC = __builtin_amdgcn_mfma_f32_32x32x16_f16(qa, b2, ACC, 0, 0, 0);         \
    MM2_LOAD(CV, (((KS) + 4) & 15))                                             \
  }

  #pragma unroll
  for (int ks = 0; ks < 16; ks += 4) {
    MM2_STAGE(c0, acc2a, ks)
    MM2_STAGE(c1, acc2b, ks + 1)
    MM2_STAGE(c2, acc2a, ks + 2)
    MM2_STAGE(c3, acc2b, ks + 3)
  }
#undef MM2_STAGE
#undef MM2_LOAD

  // ---- epilogue ----
  #pragma unroll
  for (int rr = 0; rr < 16; ++rr) {
    int row = 4 * kg + (rr & 3) + 8 * (rr >> 2);
    int col = 32 * wv + lrow;
    OUT[(row0 + row) * 256 + col] = (acc2a[rr] + acc2b[rr]) * s2s[row];
  }
}

extern "C" void kernel_launch(void* const* d_in, const int* in_sizes, int n_in,
                              void* d_out, int out_size, void* d_ws, size_t ws_size,
                              hipStream_t stream) {
  const float* X = (const float*)d_in[0];
  const float* R = (const float*)d_in[1];
  const float* CB = (const float*)d_in[2];
  float* OUT = (float*)d_out;
  const int nrows = in_sizes[0] / 256;  // 16384
  tq_main<<<nrows / 32, 512, 0, stream>>>(X, R, CB, OUT);
}